// Round 10
// baseline (366.560 us; speedup 1.0000x reference)
//
#include <hip/hip_runtime.h>
#include <hip/hip_bf16.h>
#include <math.h>

using bf16 = __hip_bfloat16;
typedef short bf16x8 __attribute__((ext_vector_type(8)));
typedef float f32x4  __attribute__((ext_vector_type(4)));

#define DMODEL 1024
#define DSTATE 16
#define DCONV  4
#define DINNER 2048
#define DTRANK 64
#define BSZ    2
#define LSEQ   2048
#define MROWS  (BSZ*LSEQ)   // 4096

#define NCHUNK 32
#define CHUNK  (LSEQ / NCHUNK)     // 64
#define DS_TOT (DINNER * DSTATE)   // 32768
#define NBCX   96                  // packed [x_proj(64) | B(16) | C(16)]
#define CONVBLK ((MROWS * DINNER) / (256 * 8))   // 4096

__device__ __forceinline__ float cvt(float v) { return v; }
__device__ __forceinline__ float cvt(bf16 v)  { return __bfloat162float(v); }

template<typename T> __device__ __forceinline__ T sto(float v);
template<> __device__ __forceinline__ float sto<float>(float v) { return v; }
template<> __device__ __forceinline__ bf16  sto<bf16>(float v)  { return __float2bfloat16(v); }

// async global->LDS 16B copy: HW writes lds_base(wave-uniform) + lane*16
__device__ __forceinline__ void gll16(const bf16* g, short* l)
{
    __builtin_amdgcn_global_load_lds(
        (const __attribute__((address_space(1))) unsigned int*)(const void*)g,
        (__attribute__((address_space(3))) unsigned int*)(void*)l,
        16, 0, 0);
}

// convert 8 f32 -> 8 bf16, 16B store (LDS or global)
__device__ __forceinline__ void cvt8_store(short* dst, float4 a, float4 b)
{
    bf16 t[8];
    t[0] = sto<bf16>(a.x); t[1] = sto<bf16>(a.y);
    t[2] = sto<bf16>(a.z); t[3] = sto<bf16>(a.w);
    t[4] = sto<bf16>(b.x); t[5] = sto<bf16>(b.y);
    t[6] = sto<bf16>(b.z); t[7] = sto<bf16>(b.w);
    *(uint4*)dst = *(const uint4*)t;
}

// -------- MFMA GEMM v3 ------------------------------------------------------
// C[m,n] = sum_k A[m,k]*W[n,k]. BM=BN=128, BK=32, 256 thr = 4 waves (2x2),
// wave = 64x64 via 4x4 frags of v_mfma_f32_16x16x32_bf16.
// Operands: bf16 -> async global_load_lds; f32 -> dbuf VGPR staging with
// inline f32->bf16 convert (load next tile before compute, commit after).
// Epilogue: acc repacked through LDS (XOR swizzle keyed (m>>2)&3, 2-way=free)
// then vectorized 16B global stores (8 per thread vs 64 scalar).
// SPLITK=1: f32 partials at out + blockIdx.z*M*N. EPI=1: softplus(v+bias[n]).
template<typename TA, typename TW, typename TO, int SPLITK, int EPI>
__global__ __launch_bounds__(256)
void gemm_mfma(const TA* __restrict__ A, const TW* __restrict__ W,
               TO* __restrict__ out, TO* __restrict__ out2,
               const float* __restrict__ bias,
               int M, int N, int K, int split, int kchunk)
{
    __shared__ __align__(16) short smem[16384];   // 32 KB total
    short* As = smem;            // [2][4096]
    short* Bs = smem + 8192;     // [2][4096]

    const int tid  = threadIdx.x;
    const int lane = tid & 63;
    const int wv   = tid >> 6;
    const int wm = (wv & 1) * 64;
    const int wn = (wv >> 1) * 64;
    const int m0 = blockIdx.y * 128;
    const int n0 = blockIdx.x * 128;

    // staging granule map (XOR swizzle: granule (r,c) -> slot r*4 + (c^((r>>1)&3)))
    const int p0 = wv * 64 + lane;
    const int p1 = p0 + 256;
    const int r0 = p0 >> 2, c0 = (p0 & 3) ^ ((r0 >> 1) & 3);
    const int r1 = p1 >> 2, c1 = (p1 & 3) ^ ((r1 >> 1) & 3);

    const TA* srcA0 = A + (size_t)(m0 + r0) * K + c0 * 8;
    const TA* srcA1 = A + (size_t)(m0 + r1) * K + c1 * 8;
    int nr0 = n0 + r0; if (nr0 >= N) nr0 = N - 1;
    int nr1 = n0 + r1; if (nr1 >= N) nr1 = N - 1;
    const TW* srcB0 = W + (size_t)nr0 * K + c0 * 8;
    const TW* srcB1 = W + (size_t)nr1 * K + c1 * 8;

    const int C4 = lane >> 4;
    const int fr = lane & 15;
    int aOff[4], bOff[4];
    #pragma unroll
    for (int i = 0; i < 4; ++i) {
        const int R = wm + i * 16 + fr;
        aOff[i] = R * 32 + ((C4 ^ ((R >> 1) & 3)) << 3);
    }
    #pragma unroll
    for (int j = 0; j < 4; ++j) {
        const int R = wn + j * 16 + fr;
        bOff[j] = R * 32 + ((C4 ^ ((R >> 1) & 3)) << 3);
    }

    f32x4 acc[4][4] = {};

    const int kb  = blockIdx.z * kchunk;
    const int nit = kchunk / 32;

    float4 la0, la1, la2, la3, lb0, lb1, lb2, lb3;

    // prologue: stage tile 0 into buffer 0
    if constexpr (sizeof(TA) == 2) {
        gll16((const bf16*)(srcA0 + kb), &As[wv * 512]);
        gll16((const bf16*)(srcA1 + kb), &As[(wv + 4) * 512]);
    } else {
        la0 = *(const float4*)(srcA0 + kb);
        la1 = *(const float4*)(srcA0 + kb + 4);
        la2 = *(const float4*)(srcA1 + kb);
        la3 = *(const float4*)(srcA1 + kb + 4);
        cvt8_store(&As[p0 * 8], la0, la1);
        cvt8_store(&As[p1 * 8], la2, la3);
    }
    if constexpr (sizeof(TW) == 2) {
        gll16((const bf16*)(srcB0 + kb), &Bs[wv * 512]);
        gll16((const bf16*)(srcB1 + kb), &Bs[(wv + 4) * 512]);
    } else {
        lb0 = *(const float4*)(srcB0 + kb);
        lb1 = *(const float4*)(srcB0 + kb + 4);
        lb2 = *(const float4*)(srcB1 + kb);
        lb3 = *(const float4*)(srcB1 + kb + 4);
        cvt8_store(&Bs[p0 * 8], lb0, lb1);
        cvt8_store(&Bs[p1 * 8], lb2, lb3);
    }

    for (int it = 0; it < nit; ++it) {
        __syncthreads();                 // buffer p ready; buffer q reads done
        const int p = it & 1;
        const int q = p ^ 1;
        const bool pf = (it + 1 < nit);
        const int k1 = kb + (it + 1) * 32;
        if (pf) {                        // issue next-tile loads (fly over compute)
            if constexpr (sizeof(TA) == 2) {
                gll16((const bf16*)(srcA0 + k1), &As[q * 4096 + wv * 512]);
                gll16((const bf16*)(srcA1 + k1), &As[q * 4096 + (wv + 4) * 512]);
            } else {
                la0 = *(const float4*)(srcA0 + k1);
                la1 = *(const float4*)(srcA0 + k1 + 4);
                la2 = *(const float4*)(srcA1 + k1);
                la3 = *(const float4*)(srcA1 + k1 + 4);
            }
            if constexpr (sizeof(TW) == 2) {
                gll16((const bf16*)(srcB0 + k1), &Bs[q * 4096 + wv * 512]);
                gll16((const bf16*)(srcB1 + k1), &Bs[q * 4096 + (wv + 4) * 512]);
            } else {
                lb0 = *(const float4*)(srcB0 + k1);
                lb1 = *(const float4*)(srcB0 + k1 + 4);
                lb2 = *(const float4*)(srcB1 + k1);
                lb3 = *(const float4*)(srcB1 + k1 + 4);
            }
        }
        bf16x8 af[4], bfr[4];
        #pragma unroll
        for (int i = 0; i < 4; ++i) af[i]  = *(const bf16x8*)&As[p * 4096 + aOff[i]];
        #pragma unroll
        for (int j = 0; j < 4; ++j) bfr[j] = *(const bf16x8*)&Bs[p * 4096 + bOff[j]];
        #pragma unroll
        for (int i = 0; i < 4; ++i)
            #pragma unroll
            for (int j = 0; j < 4; ++j)
                acc[i][j] = __builtin_amdgcn_mfma_f32_16x16x32_bf16(af[i], bfr[j], acc[i][j], 0, 0, 0);
        if (pf) {                        // commit converted tile to buffer q
            if constexpr (sizeof(TA) == 4) {
                cvt8_store(&As[q * 4096 + p0 * 8], la0, la1);
                cvt8_store(&As[q * 4096 + p1 * 8], la2, la3);
            }
            if constexpr (sizeof(TW) == 4) {
                cvt8_store(&Bs[q * 4096 + p0 * 8], lb0, lb1);
                cvt8_store(&Bs[q * 4096 + p1 * 8], lb2, lb3);
            }
        }
    }

    __syncthreads();   // all LDS reads done; smem free for epilogue repack

    const int rb = (lane >> 4) * 4;

    if constexpr (sizeof(TO) == 2) {
        // bf16 out: one pass, 128x128 bf16 = 32 KB
        bf16* cs = (bf16*)smem;
        #pragma unroll
        for (int i = 0; i < 4; ++i)
            #pragma unroll
            for (int j = 0; j < 4; ++j)
                #pragma unroll
                for (int r = 0; r < 4; ++r) {
                    const int m = wm + i * 16 + rb + r;
                    const int n = wn + j * 16 + fr;
                    float v = acc[i][j][r];
                    if (EPI == 1) {
                        v += bias[n0 + n];
                        v = (v > 20.f) ? v : log1pf(expf(v));
                    }
                    const int key = (m >> 2) & 3;
                    cs[m * 128 + (n ^ ((key & 1) << 4) ^ ((key >> 1) << 5))] = sto<bf16>(v);
                }
        __syncthreads();
        TO* ob; int nc0; int ostr;
        if (split > 0) {
            if (n0 < split) { ob = out;  nc0 = n0;         }
            else            { ob = out2; nc0 = n0 - split; }
            ostr = split;
        } else { ob = out; nc0 = n0; ostr = N; }
        #pragma unroll
        for (int g8 = 0; g8 < 8; ++g8) {
            const int G = tid + 256 * g8;
            const int mrow = G >> 4;
            const int cg = G & 15;
            const int key = (mrow >> 2) & 3;
            const int nst = (cg * 8) ^ ((key & 1) << 4) ^ ((key >> 1) << 5);
            if (n0 + nst < N) {
                const uint4 val = *(const uint4*)&cs[mrow * 128 + cg * 8];
                *(uint4*)&ob[(size_t)(m0 + mrow) * ostr + nc0 + nst] = val;
            }
        }
    } else {
        // f32 out: two n-half passes of 128x64 f32 = 32 KB
        float* fs = (float*)smem;
        float* obase = SPLITK ? ((float*)out + (size_t)blockIdx.z * M * N) : (float*)out;
        #pragma unroll
        for (int ph = 0; ph < 2; ++ph) {
            __syncthreads();
            if ((wn >> 6) == ph) {       // the 2 waves owning this n-half write
                #pragma unroll
                for (int i = 0; i < 4; ++i)
                    #pragma unroll
                    for (int j = 0; j < 4; ++j)
                        #pragma unroll
                        for (int r = 0; r < 4; ++r) {
                            const int m = wm + i * 16 + rb + r;
                            const int qq = j * 16 + fr;
                            fs[m * 64 + (qq ^ (((m >> 2) & 1) << 4))] = acc[i][j][r];
                        }
            }
            __syncthreads();
            #pragma unroll
            for (int g8 = 0; g8 < 8; ++g8) {
                const int G = tid + 256 * g8;
                const int mrow = G >> 4;
                const int cg = G & 15;
                const int qst = (cg * 4) ^ (((mrow >> 2) & 1) << 4);
                const int n_g = 64 * ph + qst;
                if (n0 + n_g < N) {
                    const float4 val = *(const float4*)&fs[mrow * 64 + cg * 4];
                    *(float4*)&obase[(size_t)(m0 + mrow) * N + n0 + n_g] = val;
                }
            }
        }
    }
}

// sum 8 split-K partials of the bcx projection; emit xr (bf16, 4096x64)
// and B|C (f32, 4096x32).
__global__ __launch_bounds__(256)
void reduce_bcx(const float* __restrict__ P8, bf16* __restrict__ xr,
                float* __restrict__ BC)
{
    const int u = blockIdx.x * 256 + threadIdx.x;   // over MROWS*NBCX
    const int m = u / NBCX;
    const int n = u - m * NBCX;
    float s = 0.f;
    #pragma unroll
    for (int k = 0; k < 8; ++k) s += P8[(size_t)k * MROWS * NBCX + u];
    if (n < 64) xr[(size_t)m * 64 + n] = sto<bf16>(s);
    else        BC[(size_t)m * 32 + (n - 64)] = s;
}

// causal depthwise conv (d_conv=4) + bias + SiLU, 8 elems/thread, 16B ldst.
// Tail blocks (>= CONVBLK) pack [x_proj;B_proj;C_proj] f32 -> bf16 96x2048.
__global__ __launch_bounds__(256)
void conv_pack(const bf16* __restrict__ x_in, const float* __restrict__ cw,
               const float* __restrict__ cb, bf16* __restrict__ x_conv,
               const float* __restrict__ xp, const float* __restrict__ Bp,
               const float* __restrict__ Cp, bf16* __restrict__ wbc)
{
    const int blk = blockIdx.x;
    if (blk >= CONVBLK) {
        const int e = ((blk - CONVBLK) * 256 + threadIdx.x) * 8;  // over 96*2048
        const int r = e >> 11, k = e & 2047;
        const float* src = (r < 64) ? (xp + (size_t)r * 2048 + k)
                         : (r < 80) ? (Bp + (size_t)(r - 64) * 2048 + k)
                                    : (Cp + (size_t)(r - 80) * 2048 + k);
        const float4 v0 = *(const float4*)src;
        const float4 v1 = *(const float4*)(src + 4);
        cvt8_store((short*)(wbc + e), v0, v1);
        return;
    }
    const size_t i8 = (size_t)(blk * 256 + threadIdx.x) * 8;
    const int d = (int)(i8 & (DINNER - 1));
    const int t = (int)((i8 >> 11) & (LSEQ - 1));
    uint4 v[4];
    const uint4 z4 = make_uint4(0, 0, 0, 0);
    v[3] = *(const uint4*)(x_in + i8);
    v[2] = (t >= 1) ? *(const uint4*)(x_in + i8 - 1 * DINNER) : z4;
    v[1] = (t >= 2) ? *(const uint4*)(x_in + i8 - 2 * DINNER) : z4;
    v[0] = (t >= 3) ? *(const uint4*)(x_in + i8 - 3 * DINNER) : z4;
    const bf16* e0 = (const bf16*)&v[0];
    const bf16* e1 = (const bf16*)&v[1];
    const bf16* e2 = (const bf16*)&v[2];
    const bf16* e3 = (const bf16*)&v[3];
    bf16 ob[8];
    #pragma unroll
    for (int e = 0; e < 8; ++e) {
        const float4 w = *(const float4*)(cw + (size_t)(d + e) * 4);
        float a = cb[d + e];
        a = fmaf(w.x, cvt(e0[e]), a);
        a = fmaf(w.y, cvt(e1[e]), a);
        a = fmaf(w.z, cvt(e2[e]), a);
        a = fmaf(w.w, cvt(e3[e]), a);
        const float sig = 1.f / (1.f + __expf(-a));
        ob[e] = sto<bf16>(a * sig);
    }
    *(uint4*)(x_conv + i8) = *(const uint4*)ob;
}

// ---------------- chunked two-phase selective scan ----------------
// B/C rows in BC buffer: row stride 32 f32, B at +0, C at +16.
__global__ __launch_bounds__(64)
void scan_phase_a(const bf16* __restrict__ x_conv, const bf16* __restrict__ dt,
                  const float* __restrict__ BC, const float* __restrict__ A_log,
                  float* __restrict__ hend, float* __restrict__ Pprod)
{
    const int lane = threadIdx.x;
    const int c = blockIdx.x;
    const int d = blockIdx.y * 64 + lane;
    const int b = blockIdx.z;

    float Af[DSTATE];
    #pragma unroll
    for (int s = 0; s < DSTATE; ++s) Af[s] = -__expf(A_log[d * DSTATE + s]);

    float h[DSTATE], P[DSTATE];
    #pragma unroll
    for (int s = 0; s < DSTATE; ++s) { h[s] = 0.f; P[s] = 1.f; }

    const size_t base = ((size_t)b * LSEQ + (size_t)c * CHUNK) * DINNER + d;
    const bf16* xp  = x_conv + base;
    const bf16* dtp = dt + base;
    const float* Bp = BC + ((size_t)b * LSEQ + (size_t)c * CHUNK) * 32;

    for (int t0 = 0; t0 < CHUNK; t0 += 4) {
        float xg[4], dtg[4];
        #pragma unroll
        for (int j = 0; j < 4; ++j) {
            xg[j]  = cvt(xp [(size_t)(t0 + j) * DINNER]);
            dtg[j] = cvt(dtp[(size_t)(t0 + j) * DINNER]);
        }
        #pragma unroll
        for (int j = 0; j < 4; ++j) {
            float Bv[DSTATE];
            const float* Br = Bp + (size_t)(t0 + j) * 32;
            *(float4*)(&Bv[0])  = *(const float4*)(Br + 0);
            *(float4*)(&Bv[4])  = *(const float4*)(Br + 4);
            *(float4*)(&Bv[8])  = *(const float4*)(Br + 8);
            *(float4*)(&Bv[12]) = *(const float4*)(Br + 12);
            const float dtv = dtg[j];
            const float dtx = dtv * xg[j];
            #pragma unroll
            for (int s = 0; s < DSTATE; ++s) {
                const float a = fmaf(dtv, Af[s], 1.0f);
                h[s] = fmaf(h[s], a, dtx * Bv[s]);
                P[s] *= a;
            }
        }
    }

    const size_t oidx = (((size_t)b * NCHUNK + c) * DINNER + d) * DSTATE;
    #pragma unroll
    for (int s = 0; s < DSTATE; ++s) {
        hend [oidx + s] = h[s];
        Pprod[oidx + s] = P[s];
    }
}

__global__ __launch_bounds__(256)
void scan_combine(float* __restrict__ hend, const float* __restrict__ Pprod)
{
    const int u = blockIdx.x * 256 + threadIdx.x;
    const int b = blockIdx.y;
    float h = 0.f;
    for (int c = 0; c < NCHUNK; ++c) {
        const size_t idx = ((size_t)b * NCHUNK + c) * DS_TOT + u;
        const float he = hend[idx];
        const float p  = Pprod[idx];
        hend[idx] = h;
        h = fmaf(p, h, he);
    }
}

__global__ __launch_bounds__(64)
void scan_phase_c(const bf16* __restrict__ x_conv, const bf16* __restrict__ dt,
                  const float* __restrict__ BC,
                  const float* __restrict__ A_log, const float* __restrict__ Dw,
                  const float* __restrict__ hin, bf16* __restrict__ zy)
{
    const int lane = threadIdx.x;
    const int c = blockIdx.x;
    const int d = blockIdx.y * 64 + lane;
    const int b = blockIdx.z;

    float Af[DSTATE];
    #pragma unroll
    for (int s = 0; s < DSTATE; ++s) Af[s] = -__expf(A_log[d * DSTATE + s]);
    const float Dv = Dw[d];

    float h[DSTATE];
    const size_t hidx = (((size_t)b * NCHUNK + c) * DINNER + d) * DSTATE;
    #pragma unroll
    for (int s = 0; s < DSTATE; ++s) h[s] = hin[hidx + s];

    const size_t base = ((size_t)b * LSEQ + (size_t)c * CHUNK) * DINNER + d;
    const bf16* xp  = x_conv + base;
    const bf16* dtp = dt + base;
    bf16*       zp  = zy + base;
    const float* Bp = BC + ((size_t)b * LSEQ + (size_t)c * CHUNK) * 32;
    const float* Cp = Bp + 16;

    for (int t0 = 0; t0 < CHUNK; t0 += 4) {
        float xg[4], dtg[4], zg[4];
        #pragma unroll
        for (int j = 0; j < 4; ++j) {
            xg[j]  = cvt(xp [(size_t)(t0 + j) * DINNER]);
            dtg[j] = cvt(dtp[(size_t)(t0 + j) * DINNER]);
            zg[j]  = cvt(zp [(size_t)(t0 + j) * DINNER]);
        }
        #pragma unroll
        for (int j = 0; j < 4; ++j) {
            float Bv[DSTATE], Cv[DSTATE];
            const float* Br = Bp + (size_t)(t0 + j) * 32;
            const float* Cr = Cp + (size_t)(t0 + j) * 32;
            *(float4*)(&Bv[0])  = *(const float4*)(Br + 0);
            *(float4*)(&Bv[4])  = *(const float4*)(Br + 4);
            *(float4*)(&Bv[8])  = *(const float4*)(Br + 8);
            *(float4*)(&Bv[12]) = *(const float4*)(Br + 12);
            *(float4*)(&Cv[0])  = *(const float4*)(Cr + 0);
            *(float4*)(&Cv[4])  = *(const float4*)(Cr + 4);
            *(float4*)(&Cv[8])  = *(const float4*)(Cr + 8);
            *(float4*)(&Cv[12]) = *(const float4*)(Cr + 12);
            const float dtv = dtg[j];
            const float dtx = dtv * xg[j];
            float y = 0.f;
            #pragma unroll
            for (int s = 0; s < DSTATE; ++s) {
                const float a = fmaf(dtv, Af[s], 1.0f);
                h[s] = fmaf(h[s], a, dtx * Bv[s]);
                y = fmaf(h[s], Cv[s], y);
            }
            const float zv = zg[j];
            const float sig = 1.f / (1.f + __expf(-zv));
            zp[(size_t)(t0 + j) * DINNER] = sto<bf16>(fmaf(Dv, xg[j], y) * (zv * sig));
        }
    }
}

extern "C" void kernel_launch(void* const* d_in, const int* in_sizes, int n_in,
                              void* d_out, int out_size, void* d_ws, size_t ws_size,
                              hipStream_t stream)
{
    const float* x          = (const float*)d_in[0];
    const float* in_proj_w  = (const float*)d_in[1];
    const float* conv_w     = (const float*)d_in[2];
    const float* conv_b     = (const float*)d_in[3];
    const float* A_log      = (const float*)d_in[4];
    const float* Dw         = (const float*)d_in[5];
    const float* dt_proj_w  = (const float*)d_in[6];
    const float* dt_proj_b  = (const float*)d_in[7];
    const float* x_proj_w   = (const float*)d_in[8];
    const float* B_proj_w   = (const float*)d_in[9];
    const float* C_proj_w   = (const float*)d_in[10];
    const float* out_proj_w = (const float*)d_in[11];
    float* out = (float*)d_out;

    // workspace (~69 MB):
    //   buf0 (MD bf16): x_in -> P8 (12.58MB over 16.78MB) -> dt
    //   buf1 (MD bf16): z -> y (scan writes in place)
    //   buf2 (MD bf16): x_conv
    //   wbc (96x2048 bf16), xr_bf (4096x64 bf16), BCbuf (4096x32 f32),
    //   hend / Pp (2x32x32768 f32 each)
    const size_t MD = (size_t)MROWS * DINNER;
    bf16* buf0  = (bf16*)d_ws;
    bf16* buf1  = buf0 + MD;
    bf16* buf2  = buf1 + MD;
    bf16* wbc   = buf2 + MD;
    bf16* xr_bf = wbc + (size_t)NBCX * DINNER;
    float* BCbuf = (float*)(xr_bf + (size_t)MROWS * DTRANK);
    float* hend  = BCbuf + (size_t)MROWS * 32;
    float* Pp    = hend + (size_t)BSZ * NCHUNK * DS_TOT;
    float* P8    = (float*)buf0;   // x_in dead after conv; dt written after reduce

    dim3 blk(256);

    // K1: xz = x @ in_proj_w^T  (f32 operands, inline cvt staging) -> x_in | z
    gemm_mfma<float, float, bf16, 0, 0><<<dim3(2 * DINNER / 128, MROWS / 128, 1), blk, 0, stream>>>(
        x, in_proj_w, buf0, buf1, nullptr, MROWS, 2 * DINNER, DMODEL, DINNER, DMODEL);

    // K2: causal depthwise conv + SiLU; tail blocks pack bcx weights -> wbc
    conv_pack<<<CONVBLK + (NBCX * DINNER) / (256 * 8), blk, 0, stream>>>(
        buf0, conv_w, conv_b, buf2, x_proj_w, B_proj_w, C_proj_w, wbc);

    // K3: fused xr|B|C projection, split-K=8, partials -> P8 (over dead x_in)
    gemm_mfma<bf16, bf16, float, 1, 0><<<dim3(1, MROWS / 128, 8), blk, 0, stream>>>(
        buf2, wbc, P8, (float*)nullptr, nullptr, MROWS, NBCX, DINNER, 0, DINNER / 8);

    // reduce partials -> xr (bf16) + B|C (f32)
    reduce_bcx<<<(MROWS * NBCX) / 256, blk, 0, stream>>>(P8, xr_bf, BCbuf);

    // K4: dt = softplus(xr @ dt_proj_w^T + b)  (K=64, f32 W inline) -> buf0
    gemm_mfma<bf16, float, bf16, 0, 1><<<dim3(DINNER / 128, MROWS / 128, 1), blk, 0, stream>>>(
        xr_bf, dt_proj_w, buf0, (bf16*)nullptr, dt_proj_b, MROWS, DINNER, DTRANK, 0, DTRANK);

    // K5: chunked two-phase selective scan (y over z in place in buf1)
    scan_phase_a<<<dim3(NCHUNK, DINNER / 64, BSZ), dim3(64), 0, stream>>>(
        buf2, buf0, BCbuf, A_log, hend, Pp);
    scan_combine<<<dim3(DS_TOT / 256, BSZ), dim3(256), 0, stream>>>(hend, Pp);
    scan_phase_c<<<dim3(NCHUNK, DINNER / 64, BSZ), dim3(64), 0, stream>>>(
        buf2, buf0, BCbuf, A_log, Dw, hend, buf1);

    // K6: out = y @ out_proj_w^T  (f32 W inline) -> f32 d_out
    gemm_mfma<bf16, float, float, 0, 0><<<dim3(DMODEL / 128, MROWS / 128, 1), blk, 0, stream>>>(
        buf1, out_proj_w, out, (float*)nullptr, nullptr, MROWS, DMODEL, DINNER, 0, DINNER);
}

// Round 11
// 326.957 us; speedup vs baseline: 1.1211x; 1.1211x over previous
//
#include <hip/hip_runtime.h>
#include <hip/hip_bf16.h>
#include <math.h>

using bf16 = __hip_bfloat16;
typedef short bf16x8 __attribute__((ext_vector_type(8)));
typedef float f32x4  __attribute__((ext_vector_type(4)));

#define DMODEL 1024
#define DSTATE 16
#define DCONV  4
#define DINNER 2048
#define DTRANK 64
#define BSZ    2
#define LSEQ   2048
#define MROWS  (BSZ*LSEQ)   // 4096

#define NCHUNK 32
#define CHUNK  (LSEQ / NCHUNK)     // 64
#define DS_TOT (DINNER * DSTATE)   // 32768
#define NBCX   96                  // packed [x_proj(64) | B(16) | C(16)]

__device__ __forceinline__ float cvt(float v) { return v; }
__device__ __forceinline__ float cvt(bf16 v)  { return __bfloat162float(v); }

template<typename T> __device__ __forceinline__ T sto(float v);
template<> __device__ __forceinline__ float sto<float>(float v) { return v; }
template<> __device__ __forceinline__ bf16  sto<bf16>(float v)  { return __float2bfloat16(v); }

// async global->LDS 16B copy: HW writes lds_base(wave-uniform) + lane*16
__device__ __forceinline__ void gll16(const bf16* g, short* l)
{
    __builtin_amdgcn_global_load_lds(
        (const __attribute__((address_space(1))) unsigned int*)(const void*)g,
        (__attribute__((address_space(3))) unsigned int*)(void*)l,
        16, 0, 0);
}

// -- fused f32->bf16 convert: x | in_proj_w | out_proj_w | dt_proj_w | bcx --
__global__ __launch_bounds__(256)
void cvt_all(const float* __restrict__ a, const float* __restrict__ b,
             const float* __restrict__ c, const float* __restrict__ d,
             const float* __restrict__ xp, const float* __restrict__ Bp,
             const float* __restrict__ Cp,
             bf16* __restrict__ oa, bf16* __restrict__ ob, bf16* __restrict__ oc,
             bf16* __restrict__ od, bf16* __restrict__ obcx,
             int na, int nb, int nc, int nd, int nbcx)
{
    const int idx = (blockIdx.x * 256 + threadIdx.x) * 4;
    const float* src; bf16* dst; int off;
    if (idx < na)                      { src = a; dst = oa; off = idx; }
    else if (idx < na + nb)            { src = b; dst = ob; off = idx - na; }
    else if (idx < na + nb + nc)       { src = c; dst = oc; off = idx - na - nb; }
    else if (idx < na + nb + nc + nd)  { src = d; dst = od; off = idx - na - nb - nc; }
    else if (idx < na+nb+nc+nd+nbcx) {
        off = idx - na - nb - nc - nd;
        const int r = off >> 11, k = off & 2047;
        src = (r < 64) ? (xp + (size_t)r * 2048 + k)
            : (r < 80) ? (Bp + (size_t)(r - 64) * 2048 + k)
                       : (Cp + (size_t)(r - 80) * 2048 + k);
        src -= off;
        dst = obcx;
    } else return;
    const float4 v = *(const float4*)(src + off);
    dst[off + 0] = sto<bf16>(v.x); dst[off + 1] = sto<bf16>(v.y);
    dst[off + 2] = sto<bf16>(v.z); dst[off + 3] = sto<bf16>(v.w);
}

// -------- MFMA GEMM: bf16 async-LDS dbuf staging + vectorized epilogue -----
// C[m,n] = sum_k A[m,k]*W[n,k]. BM=BN=128, BK=32, 256 thr = 4 waves (2x2),
// wave = 64x64 via 4x4 frags of v_mfma_f32_16x16x32_bf16.
// Staging granule (16B) for (row r, kchunk c) at slot r*4 + (c^((r>>1)&3)).
// Epilogue: acc repacked through (now dead) staging LDS with XOR swizzle
// keyed (m>>2)&3 (2-way bank access = free), then 16B coalesced stores.
// SPLITK=1: f32 partials at out + blockIdx.z*M*N. EPI=1: softplus(v+bias[n]).
template<typename TO, int SPLITK, int EPI>
__global__ __launch_bounds__(256)
void gemm_mfma(const bf16* __restrict__ A, const bf16* __restrict__ W,
               TO* __restrict__ out, TO* __restrict__ out2,
               const float* __restrict__ bias,
               int M, int N, int K, int split, int kchunk)
{
    __shared__ __align__(16) short smem[16384];   // 32 KB
    short* As = smem;            // [2][4096]
    short* Bs = smem + 8192;     // [2][4096]

    const int tid  = threadIdx.x;
    const int lane = tid & 63;
    const int wv   = tid >> 6;
    const int wm = (wv & 1) * 64;
    const int wn = (wv >> 1) * 64;
    const int m0 = blockIdx.y * 128;
    const int n0 = blockIdx.x * 128;

    const int p0 = wv * 64 + lane;
    const int p1 = p0 + 256;
    const int r0 = p0 >> 2, c0 = (p0 & 3) ^ ((r0 >> 1) & 3);
    const int r1 = p1 >> 2, c1 = (p1 & 3) ^ ((r1 >> 1) & 3);

    const bf16* srcA0 = A + (size_t)(m0 + r0) * K + c0 * 8;
    const bf16* srcA1 = A + (size_t)(m0 + r1) * K + c1 * 8;
    int nr0 = n0 + r0; if (nr0 >= N) nr0 = N - 1;
    int nr1 = n0 + r1; if (nr1 >= N) nr1 = N - 1;
    const bf16* srcB0 = W + (size_t)nr0 * K + c0 * 8;
    const bf16* srcB1 = W + (size_t)nr1 * K + c1 * 8;

    const int C4 = lane >> 4;
    const int fr = lane & 15;
    int aOff[4], bOff[4];
    #pragma unroll
    for (int i = 0; i < 4; ++i) {
        const int R = wm + i * 16 + fr;
        aOff[i] = R * 32 + ((C4 ^ ((R >> 1) & 3)) << 3);
    }
    #pragma unroll
    for (int j = 0; j < 4; ++j) {
        const int R = wn + j * 16 + fr;
        bOff[j] = R * 32 + ((C4 ^ ((R >> 1) & 3)) << 3);
    }

    f32x4 acc[4][4] = {};

    const int kb  = blockIdx.z * kchunk;
    const int nit = kchunk / 32;

    // prologue: stage tile 0 into buffer 0
    gll16(srcA0 + kb, &As[wv * 512]);
    gll16(srcA1 + kb, &As[(wv + 4) * 512]);
    gll16(srcB0 + kb, &Bs[wv * 512]);
    gll16(srcB1 + kb, &Bs[(wv + 4) * 512]);

    for (int it = 0; it < nit; ++it) {
        __syncthreads();                 // buf p ready; prior reads of buf q done
        const int p = it & 1;
        if (it + 1 < nit) {
            const int q  = p ^ 1;
            const int k1 = kb + (it + 1) * 32;
            gll16(srcA0 + k1, &As[q * 4096 + wv * 512]);
            gll16(srcA1 + k1, &As[q * 4096 + (wv + 4) * 512]);
            gll16(srcB0 + k1, &Bs[q * 4096 + wv * 512]);
            gll16(srcB1 + k1, &Bs[q * 4096 + (wv + 4) * 512]);
        }
        bf16x8 af[4], bfr[4];
        #pragma unroll
        for (int i = 0; i < 4; ++i) af[i]  = *(const bf16x8*)&As[p * 4096 + aOff[i]];
        #pragma unroll
        for (int j = 0; j < 4; ++j) bfr[j] = *(const bf16x8*)&Bs[p * 4096 + bOff[j]];
        #pragma unroll
        for (int i = 0; i < 4; ++i)
            #pragma unroll
            for (int j = 0; j < 4; ++j)
                acc[i][j] = __builtin_amdgcn_mfma_f32_16x16x32_bf16(af[i], bfr[j], acc[i][j], 0, 0, 0);
    }

    __syncthreads();   // all LDS reads done; smem free for epilogue repack

    const int rb = (lane >> 4) * 4;

    if constexpr (sizeof(TO) == 2) {
        // bf16 out: one pass, 128x128 bf16 = 32 KB
        bf16* cs = (bf16*)smem;
        #pragma unroll
        for (int i = 0; i < 4; ++i)
            #pragma unroll
            for (int j = 0; j < 4; ++j)
                #pragma unroll
                for (int r = 0; r < 4; ++r) {
                    const int m = wm + i * 16 + rb + r;
                    const int n = wn + j * 16 + fr;
                    float v = acc[i][j][r];
                    if (EPI == 1) {
                        v += bias[n0 + n];
                        v = (v > 20.f) ? v : log1pf(expf(v));
                    }
                    const int key = (m >> 2) & 3;
                    cs[m * 128 + (n ^ ((key & 1) << 4) ^ ((key >> 1) << 5))] = sto<bf16>(v);
                }
        __syncthreads();
        TO* ob; int nc0; int ostr;
        if (split > 0) {
            if (n0 < split) { ob = out;  nc0 = n0;         }
            else            { ob = out2; nc0 = n0 - split; }
            ostr = split;
        } else { ob = out; nc0 = n0; ostr = N; }
        #pragma unroll
        for (int g8 = 0; g8 < 8; ++g8) {
            const int G = tid + 256 * g8;
            const int mrow = G >> 4;
            const int cg = G & 15;
            const int key = (mrow >> 2) & 3;
            const int nst = (cg * 8) ^ ((key & 1) << 4) ^ ((key >> 1) << 5);
            if (n0 + nst < N) {
                const uint4 val = *(const uint4*)&cs[mrow * 128 + cg * 8];
                *(uint4*)&ob[(size_t)(m0 + mrow) * ostr + nc0 + nst] = val;
            }
        }
    } else {
        // f32 out: two n-half passes of 128x64 f32 = 32 KB
        float* fs = (float*)smem;
        float* obase = SPLITK ? ((float*)out + (size_t)blockIdx.z * M * N) : (float*)out;
        #pragma unroll
        for (int ph = 0; ph < 2; ++ph) {
            __syncthreads();
            if ((wn >> 6) == ph) {       // the 2 waves owning this n-half write
                #pragma unroll
                for (int i = 0; i < 4; ++i)
                    #pragma unroll
                    for (int j = 0; j < 4; ++j)
                        #pragma unroll
                        for (int r = 0; r < 4; ++r) {
                            const int m = wm + i * 16 + rb + r;
                            const int qq = j * 16 + fr;
                            fs[m * 64 + (qq ^ (((m >> 2) & 1) << 4))] = acc[i][j][r];
                        }
            }
            __syncthreads();
            #pragma unroll
            for (int g8 = 0; g8 < 8; ++g8) {
                const int G = tid + 256 * g8;
                const int mrow = G >> 4;
                const int cg = G & 15;
                const int qst = (cg * 4) ^ (((mrow >> 2) & 1) << 4);
                const int n_g = 64 * ph + qst;
                if (n0 + n_g < N) {
                    const float4 val = *(const float4*)&fs[mrow * 64 + cg * 4];
                    *(float4*)&obase[(size_t)(m0 + mrow) * N + n0 + n_g] = val;
                }
            }
        }
    }
}

// sum 8 split-K partials of the bcx projection; emit xr (bf16, 4096x64)
// and B|C (f32, 4096x32).
__global__ __launch_bounds__(256)
void reduce_bcx(const float* __restrict__ P8, bf16* __restrict__ xr,
                float* __restrict__ BC)
{
    const int u = blockIdx.x * 256 + threadIdx.x;   // over MROWS*NBCX
    const int m = u / NBCX;
    const int n = u - m * NBCX;
    float s = 0.f;
    #pragma unroll
    for (int k = 0; k < 8; ++k) s += P8[(size_t)k * MROWS * NBCX + u];
    if (n < 64) xr[(size_t)m * 64 + n] = sto<bf16>(s);
    else        BC[(size_t)m * 32 + (n - 64)] = s;
}

// causal depthwise conv (d_conv=4) + bias + SiLU, 8 elems/thread, 16B ldst
__global__ __launch_bounds__(256)
void conv_silu(const bf16* __restrict__ x_in, const float* __restrict__ cw,
               const float* __restrict__ cb, bf16* __restrict__ x_conv)
{
    const size_t i8 = (size_t)(blockIdx.x * 256 + threadIdx.x) * 8;
    const int d = (int)(i8 & (DINNER - 1));
    const int t = (int)((i8 >> 11) & (LSEQ - 1));
    uint4 v[4];
    const uint4 z4 = make_uint4(0, 0, 0, 0);
    v[3] = *(const uint4*)(x_in + i8);
    v[2] = (t >= 1) ? *(const uint4*)(x_in + i8 - 1 * DINNER) : z4;
    v[1] = (t >= 2) ? *(const uint4*)(x_in + i8 - 2 * DINNER) : z4;
    v[0] = (t >= 3) ? *(const uint4*)(x_in + i8 - 3 * DINNER) : z4;
    const bf16* e0 = (const bf16*)&v[0];
    const bf16* e1 = (const bf16*)&v[1];
    const bf16* e2 = (const bf16*)&v[2];
    const bf16* e3 = (const bf16*)&v[3];
    bf16 ob[8];
    #pragma unroll
    for (int e = 0; e < 8; ++e) {
        const float4 w = *(const float4*)(cw + (size_t)(d + e) * 4);
        float a = cb[d + e];
        a = fmaf(w.x, cvt(e0[e]), a);
        a = fmaf(w.y, cvt(e1[e]), a);
        a = fmaf(w.z, cvt(e2[e]), a);
        a = fmaf(w.w, cvt(e3[e]), a);
        const float sig = 1.f / (1.f + __expf(-a));
        ob[e] = sto<bf16>(a * sig);
    }
    *(uint4*)(x_conv + i8) = *(const uint4*)ob;
}

// ---------------- chunked two-phase selective scan ----------------
// B/C rows in BC buffer: row stride 32 f32, B at +0, C at +16.
__global__ __launch_bounds__(64)
void scan_phase_a(const bf16* __restrict__ x_conv, const bf16* __restrict__ dt,
                  const float* __restrict__ BC, const float* __restrict__ A_log,
                  float* __restrict__ hend, float* __restrict__ Pprod)
{
    const int lane = threadIdx.x;
    const int c = blockIdx.x;
    const int d = blockIdx.y * 64 + lane;
    const int b = blockIdx.z;

    float Af[DSTATE];
    #pragma unroll
    for (int s = 0; s < DSTATE; ++s) Af[s] = -__expf(A_log[d * DSTATE + s]);

    float h[DSTATE], P[DSTATE];
    #pragma unroll
    for (int s = 0; s < DSTATE; ++s) { h[s] = 0.f; P[s] = 1.f; }

    const size_t base = ((size_t)b * LSEQ + (size_t)c * CHUNK) * DINNER + d;
    const bf16* xp  = x_conv + base;
    const bf16* dtp = dt + base;
    const float* Bp = BC + ((size_t)b * LSEQ + (size_t)c * CHUNK) * 32;

    for (int t0 = 0; t0 < CHUNK; t0 += 4) {
        float xg[4], dtg[4];
        #pragma unroll
        for (int j = 0; j < 4; ++j) {
            xg[j]  = cvt(xp [(size_t)(t0 + j) * DINNER]);
            dtg[j] = cvt(dtp[(size_t)(t0 + j) * DINNER]);
        }
        #pragma unroll
        for (int j = 0; j < 4; ++j) {
            float Bv[DSTATE];
            const float* Br = Bp + (size_t)(t0 + j) * 32;
            *(float4*)(&Bv[0])  = *(const float4*)(Br + 0);
            *(float4*)(&Bv[4])  = *(const float4*)(Br + 4);
            *(float4*)(&Bv[8])  = *(const float4*)(Br + 8);
            *(float4*)(&Bv[12]) = *(const float4*)(Br + 12);
            const float dtv = dtg[j];
            const float dtx = dtv * xg[j];
            #pragma unroll
            for (int s = 0; s < DSTATE; ++s) {
                const float a = fmaf(dtv, Af[s], 1.0f);
                h[s] = fmaf(h[s], a, dtx * Bv[s]);
                P[s] *= a;
            }
        }
    }

    const size_t oidx = (((size_t)b * NCHUNK + c) * DINNER + d) * DSTATE;
    #pragma unroll
    for (int s = 0; s < DSTATE; ++s) {
        hend [oidx + s] = h[s];
        Pprod[oidx + s] = P[s];
    }
}

__global__ __launch_bounds__(256)
void scan_combine(float* __restrict__ hend, const float* __restrict__ Pprod)
{
    const int u = blockIdx.x * 256 + threadIdx.x;
    const int b = blockIdx.y;
    float h = 0.f;
    for (int c = 0; c < NCHUNK; ++c) {
        const size_t idx = ((size_t)b * NCHUNK + c) * DS_TOT + u;
        const float he = hend[idx];
        const float p  = Pprod[idx];
        hend[idx] = h;
        h = fmaf(p, h, he);
    }
}

__global__ __launch_bounds__(64)
void scan_phase_c(const bf16* __restrict__ x_conv, const bf16* __restrict__ dt,
                  const float* __restrict__ BC,
                  const float* __restrict__ A_log, const float* __restrict__ Dw,
                  const float* __restrict__ hin, bf16* __restrict__ zy)
{
    const int lane = threadIdx.x;
    const int c = blockIdx.x;
    const int d = blockIdx.y * 64 + lane;
    const int b = blockIdx.z;

    float Af[DSTATE];
    #pragma unroll
    for (int s = 0; s < DSTATE; ++s) Af[s] = -__expf(A_log[d * DSTATE + s]);
    const float Dv = Dw[d];

    float h[DSTATE];
    const size_t hidx = (((size_t)b * NCHUNK + c) * DINNER + d) * DSTATE;
    #pragma unroll
    for (int s = 0; s < DSTATE; ++s) h[s] = hin[hidx + s];

    const size_t base = ((size_t)b * LSEQ + (size_t)c * CHUNK) * DINNER + d;
    const bf16* xp  = x_conv + base;
    const bf16* dtp = dt + base;
    bf16*       zp  = zy + base;
    const float* Bp = BC + ((size_t)b * LSEQ + (size_t)c * CHUNK) * 32;
    const float* Cp = Bp + 16;

    for (int t0 = 0; t0 < CHUNK; t0 += 4) {
        float xg[4], dtg[4], zg[4];
        #pragma unroll
        for (int j = 0; j < 4; ++j) {
            xg[j]  = cvt(xp [(size_t)(t0 + j) * DINNER]);
            dtg[j] = cvt(dtp[(size_t)(t0 + j) * DINNER]);
            zg[j]  = cvt(zp [(size_t)(t0 + j) * DINNER]);
        }
        #pragma unroll
        for (int j = 0; j < 4; ++j) {
            float Bv[DSTATE], Cv[DSTATE];
            const float* Br = Bp + (size_t)(t0 + j) * 32;
            const float* Cr = Cp + (size_t)(t0 + j) * 32;
            *(float4*)(&Bv[0])  = *(const float4*)(Br + 0);
            *(float4*)(&Bv[4])  = *(const float4*)(Br + 4);
            *(float4*)(&Bv[8])  = *(const float4*)(Br + 8);
            *(float4*)(&Bv[12]) = *(const float4*)(Br + 12);
            *(float4*)(&Cv[0])  = *(const float4*)(Cr + 0);
            *(float4*)(&Cv[4])  = *(const float4*)(Cr + 4);
            *(float4*)(&Cv[8])  = *(const float4*)(Cr + 8);
            *(float4*)(&Cv[12]) = *(const float4*)(Cr + 12);
            const float dtv = dtg[j];
            const float dtx = dtv * xg[j];
            float y = 0.f;
            #pragma unroll
            for (int s = 0; s < DSTATE; ++s) {
                const float a = fmaf(dtv, Af[s], 1.0f);
                h[s] = fmaf(h[s], a, dtx * Bv[s]);
                y = fmaf(h[s], Cv[s], y);
            }
            const float zv = zg[j];
            const float sig = 1.f / (1.f + __expf(-zv));
            zp[(size_t)(t0 + j) * DINNER] = sto<bf16>(fmaf(Dv, xg[j], y) * (zv * sig));
        }
    }
}

extern "C" void kernel_launch(void* const* d_in, const int* in_sizes, int n_in,
                              void* d_out, int out_size, void* d_ws, size_t ws_size,
                              hipStream_t stream)
{
    const float* x          = (const float*)d_in[0];
    const float* in_proj_w  = (const float*)d_in[1];
    const float* conv_w     = (const float*)d_in[2];
    const float* conv_b     = (const float*)d_in[3];
    const float* A_log      = (const float*)d_in[4];
    const float* Dw         = (const float*)d_in[5];
    const float* dt_proj_w  = (const float*)d_in[6];
    const float* dt_proj_b  = (const float*)d_in[7];
    const float* x_proj_w   = (const float*)d_in[8];
    const float* B_proj_w   = (const float*)d_in[9];
    const float* C_proj_w   = (const float*)d_in[10];
    const float* out_proj_w = (const float*)d_in[11];
    float* out = (float*)d_out;

    // workspace (~93 MB, with aliasing) — identical to R9 layout
    const size_t MD = (size_t)MROWS * DINNER;
    bf16* buf0 = (bf16*)d_ws;                        // x_in -> P8 -> dt
    bf16* buf1 = buf0 + MD;                          // z -> y (in place)
    bf16* buf2 = buf1 + MD;                          // x_conv
    bf16* xbf  = buf2 + MD;                          // x bf16 (dead after K1)
    bf16* wbf1 = xbf  + (size_t)MROWS * DMODEL;      // in_proj bf16
    bf16* wbf2 = wbf1 + (size_t)2 * DINNER * DMODEL; // out_proj bf16
    bf16* wbc  = wbf2 + (size_t)DMODEL * DINNER;     // packed bcx weights bf16
    bf16* wdt  = wbc  + (size_t)NBCX * DINNER;       // dt_proj_w bf16
    float* hend = (float*)(wdt + (size_t)DINNER * DTRANK);
    float* Pp   = hend + (size_t)BSZ * NCHUNK * DS_TOT;
    // aliases over dead regions:
    bf16*  xr_bf = xbf;                              // 4096x64 bf16 (xbf dead after K1)
    float* BCbuf = (float*)(xbf + (size_t)MROWS * DTRANK); // 4096x32 f32
    float* P8 = (float*)buf0;  // 12.58 MB over buf0 (16.78): x_in dead after conv

    dim3 blk(256);
    const int na = MROWS * DMODEL;
    const int nb = 2 * DINNER * DMODEL;
    const int nc = DMODEL * DINNER;
    const int nd = DINNER * DTRANK;
    const int nbcx = NBCX * DINNER;

    // fused f32->bf16 converts + weight pack
    cvt_all<<<(na + nb + nc + nd + nbcx) / 1024, blk, 0, stream>>>(
        x, in_proj_w, out_proj_w, dt_proj_w, x_proj_w, B_proj_w, C_proj_w,
        xbf, wbf1, wbf2, wdt, wbc, na, nb, nc, nd, nbcx);

    // K1: xz = x @ in_proj_w^T (MFMA dbuf), split into x_in | z
    gemm_mfma<bf16, 0, 0><<<dim3(2 * DINNER / 128, MROWS / 128, 1), blk, 0, stream>>>(
        xbf, wbf1, buf0, buf1, nullptr, MROWS, 2 * DINNER, DMODEL, DINNER, DMODEL);

    // K2: causal depthwise conv + SiLU
    conv_silu<<<(MROWS * DINNER) / (256 * 8), blk, 0, stream>>>(buf0, conv_w, conv_b, buf2);

    // K3: fused xr|B|C projection, split-K=8, partials -> P8 (over dead x_in)
    gemm_mfma<float, 1, 0><<<dim3(1, MROWS / 128, 8), blk, 0, stream>>>(
        buf2, wbc, P8, (float*)nullptr, nullptr, MROWS, NBCX, DINNER, 0, DINNER / 8);

    // reduce partials -> xr (bf16) + B|C (f32)
    reduce_bcx<<<(MROWS * NBCX) / 256, blk, 0, stream>>>(P8, xr_bf, BCbuf);

    // K4: dt = softplus(xr @ dt_proj_w^T + b)  (MFMA, K=64) -> buf0 (over dead P8)
    gemm_mfma<bf16, 0, 1><<<dim3(DINNER / 128, MROWS / 128, 1), blk, 0, stream>>>(
        xr_bf, wdt, buf0, (bf16*)nullptr, dt_proj_b, MROWS, DINNER, DTRANK, 0, DTRANK);

    // K5: chunked two-phase selective scan (y over z in place in buf1)
    scan_phase_a<<<dim3(NCHUNK, DINNER / 64, BSZ), dim3(64), 0, stream>>>(
        buf2, buf0, BCbuf, A_log, hend, Pp);
    scan_combine<<<dim3(DS_TOT / 256, BSZ), dim3(256), 0, stream>>>(hend, Pp);
    scan_phase_c<<<dim3(NCHUNK, DINNER / 64, BSZ), dim3(64), 0, stream>>>(
        buf2, buf0, BCbuf, A_log, Dw, hend, buf1);

    // K6: out = y @ out_proj_w^T (MFMA dbuf) -> f32 d_out
    gemm_mfma<float, 0, 0><<<dim3(DMODEL / 128, MROWS / 128, 1), blk, 0, stream>>>(
        buf1, wbf2, out, (float*)nullptr, nullptr, MROWS, DMODEL, DINNER, 0, DINNER);
}